// Round 2
// 430.393 us; speedup vs baseline: 1.0115x; 1.0115x over previous
//
#include <hip/hip_runtime.h>

#define MARGIN   0.3f
#define S_SCALE  15.0f
#define LAMDA    2.0f
#define NB       8192
#define NC       10000
#define MAXLOGIT 15.0f   // logits = 15*costh, costh in [0,1] -> fixed, safe shift

// One block per row. 2500 float4 per row, 256 threads -> 9 full strided loads
// per thread + 1 guarded tail load (tid < 196). All loads are issued into
// registers up front (compile-time unroll -> 9-10 loads in flight per wave,
// vs ~1 for the old dynamic-trip rolled loop), then consumed. Summation order
// is bitwise-identical to the previous passing kernel.
__global__ __launch_bounds__(256) void dam_row_loss(const float* __restrict__ costh,
                                                    const int* __restrict__ label,
                                                    float* __restrict__ row_loss) {
    const int row = blockIdx.x;
    const int tid = threadIdx.x;
    const float* __restrict__ rowp = costh + (size_t)row * NC;
    const float4* __restrict__ rp4 = (const float4*)rowp;  // 40000 B rows: 16B aligned

    // Prefetch the (broadcast) label + target cosine early so thread 0's
    // dependent tail is hidden under the bulk loads.
    const int lbl = label[row];

    float4 v[9];
    #pragma unroll
    for (int j = 0; j < 9; ++j) v[j] = rp4[tid + (j << 8)];   // idx <= 255+2048 < 2500
    const bool tail_ok = (tid < 196);                         // tid+2304 < 2500
    float4 vt = make_float4(0.f, 0.f, 0.f, 0.f);
    if (tail_ok) vt = rp4[tid + 2304];

    const float cos_t = rowp[lbl];   // broadcast load (row is L2-hot)

    float s = 0.0f;
    #pragma unroll
    for (int j = 0; j < 9; ++j) {
        s += __expf(fmaf(S_SCALE, v[j].x, -MAXLOGIT));
        s += __expf(fmaf(S_SCALE, v[j].y, -MAXLOGIT));
        s += __expf(fmaf(S_SCALE, v[j].z, -MAXLOGIT));
        s += __expf(fmaf(S_SCALE, v[j].w, -MAXLOGIT));
    }
    if (tail_ok) {
        s += __expf(fmaf(S_SCALE, vt.x, -MAXLOGIT));
        s += __expf(fmaf(S_SCALE, vt.y, -MAXLOGIT));
        s += __expf(fmaf(S_SCALE, vt.z, -MAXLOGIT));
        s += __expf(fmaf(S_SCALE, vt.w, -MAXLOGIT));
    }

    // wave64 shuffle reduce, then across the 4 waves via LDS (same tree as before)
    #pragma unroll
    for (int off = 32; off > 0; off >>= 1)
        s += __shfl_down(s, off, 64);
    __shared__ float wsum[4];
    if ((tid & 63) == 0) wsum[tid >> 6] = s;
    __syncthreads();

    if (tid == 0) {
        float tot = wsum[0] + wsum[1] + wsum[2] + wsum[3];
        const float delta = (MARGIN / LAMDA) * __expf(1.0f - cos_t);
        const float t_logit = S_SCALE * (cos_t - delta);           // modified target logit
        // swap original target term for the margin-adjusted one
        tot = tot - __expf(fmaf(S_SCALE, cos_t, -MAXLOGIT)) + __expf(t_logit - MAXLOGIT);
        const float lse = MAXLOGIT + __logf(tot);
        row_loss[row] = lse - t_logit;                             // -logp[target]
    }
}

// 8192 floats -> scalar mean. Single block; trip count is compile-time (32),
// full unroll keeps all loads in flight; same add order as before.
__global__ __launch_bounds__(256) void dam_reduce(const float* __restrict__ row_loss,
                                                  float* __restrict__ out) {
    const int tid = threadIdx.x;
    float s = 0.0f;
    #pragma unroll
    for (int i = tid; i < NB; i += 256) s += row_loss[i];
    #pragma unroll
    for (int off = 32; off > 0; off >>= 1)
        s += __shfl_down(s, off, 64);
    __shared__ float wsum[4];
    if ((tid & 63) == 0) wsum[tid >> 6] = s;
    __syncthreads();
    if (tid == 0) out[0] = (wsum[0] + wsum[1] + wsum[2] + wsum[3]) * (1.0f / (float)NB);
}

extern "C" void kernel_launch(void* const* d_in, const int* in_sizes, int n_in,
                              void* d_out, int out_size, void* d_ws, size_t ws_size,
                              hipStream_t stream) {
    const float* costh = (const float*)d_in[0];
    const int*   label = (const int*)d_in[1];
    float* out = (float*)d_out;
    float* row_loss = (float*)d_ws;  // 8192 floats = 32 KB scratch

    dam_row_loss<<<NB, 256, 0, stream>>>(costh, label, row_loss);
    dam_reduce<<<1, 256, 0, stream>>>(row_loss, out);
}